// Round 1
// baseline (1074.269 us; speedup 1.0000x reference)
//
#include <hip/hip_runtime.h>

#define GLOBAL_AS __attribute__((address_space(1)))
#define LDS_AS    __attribute__((address_space(3)))

typedef short bf16x8 __attribute__((ext_vector_type(8)));
typedef float f32x4  __attribute__((ext_vector_type(4)));

// Problem shape (fixed by setup_inputs)
#define M_DIM 8192     // B*S = 4*2048
#define N_DIM 4096     // DOUT
#define K_DIM 4096     // DIN
#define R_DIM 16
#define KAUG 4128      // K_DIM + 32 (16 lora cols + 16 zero pad)
#define KTILES 129     // 4128/32

__constant__ float NF4C[16] = {
    -1.0f, -0.6961928009986877f, -0.5250730514526367f, -0.39491748809814453f,
    -0.28444138169288635f, -0.18477343022823334f, -0.09105003625154495f, 0.0f,
    0.07958029955625534f, 0.16093020141124725f, 0.24611230194568634f,
    0.33791524171829224f, 0.44070982933044434f, 0.5626170039176941f,
    0.7229568362236023f, 1.0f};

__device__ __forceinline__ unsigned short f2bf(float f) {
    unsigned int u = __float_as_uint(f);
    u += 0x7fffu + ((u >> 16) & 1u);   // round-to-nearest-even
    return (unsigned short)(u >> 16);
}
__device__ __forceinline__ float bf2f(unsigned short s) {
    return __uint_as_float(((unsigned int)s) << 16);
}

// ---- prep 1: x fp32 -> bf16 into xb[M][KAUG] cols 0..4095 ----
__global__ void convert_x_kernel(const float4* __restrict__ x4,
                                 unsigned short* __restrict__ xb) {
    int idx = blockIdx.x * 256 + threadIdx.x;   // float4 index, 8192*1024 total
    int m = idx >> 10;
    int k = (idx & 1023) * 4;
    float4 v = x4[idx];
    ushort4 o;
    o.x = f2bf(v.x); o.y = f2bf(v.y); o.z = f2bf(v.z); o.w = f2bf(v.w);
    *(ushort4*)(xb + (size_t)m * KAUG + k) = o;
}

// ---- prep 2: NF4 dequant -> wq[N][KAUG] cols 0..4095 ----
__global__ void dequant_kernel(const int4* __restrict__ codes4,
                               const float* __restrict__ absmax,
                               unsigned short* __restrict__ wq) {
    int idx = blockIdx.x * 256 + threadIdx.x;   // int4 index, 4096*1024 total
    int n = idx >> 10;
    int k = (idx & 1023) * 4;
    float am = absmax[n * 64 + (k >> 6)];
    int4 c = codes4[idx];
    ushort4 o;
    o.x = f2bf(NF4C[c.x] * am);
    o.y = f2bf(NF4C[c.y] * am);
    o.z = f2bf(NF4C[c.z] * am);
    o.w = f2bf(NF4C[c.w] * am);
    *(ushort4*)(wq + (size_t)n * KAUG + k) = o;
}

// ---- prep 3: wq cols 4096..4127 = 2*lora_B | zeros ----
__global__ void lora_b_fill_kernel(const float* __restrict__ loraB,
                                   unsigned short* __restrict__ wq) {
    int idx = blockIdx.x * 256 + threadIdx.x;   // 4096*32 total
    int n = idx >> 5;
    int c = idx & 31;
    float v = (c < R_DIM) ? 2.0f * loraB[n * R_DIM + c] : 0.0f;
    wq[(size_t)n * KAUG + K_DIM + c] = f2bf(v);
}

// ---- prep 4: a = x @ A^T -> xb cols 4096..4111 (bf16), 4112..4127 zero ----
// one wave per row m; A staged in LDS as bf16 in 32KB chunks
__global__ void lora_a_kernel(const float4* __restrict__ x4,
                              const float4* __restrict__ A4,
                              unsigned short* __restrict__ xb) {
    __shared__ __align__(16) unsigned short As[16 * 1024];   // 32 KB chunk
    const int tid = threadIdx.x;
    const int wave = tid >> 6, lane = tid & 63;
    const int m = blockIdx.x * 4 + wave;
    float acc[16];
#pragma unroll
    for (int r = 0; r < 16; ++r) acc[r] = 0.0f;

    for (int c = 0; c < 4; ++c) {
        __syncthreads();
        // stage A[16][c*1024 .. +1024) as bf16: 4096 float4s, 16/thread
#pragma unroll
        for (int p = 0; p < 16; ++p) {
            int f4 = tid + p * 256;          // 0..4095
            int r = f4 >> 8, kk4 = f4 & 255;
            float4 v = A4[r * 1024 + c * 256 + kk4];
            ushort4 o;
            o.x = f2bf(v.x); o.y = f2bf(v.y); o.z = f2bf(v.z); o.w = f2bf(v.w);
            *(ushort4*)(&As[f4 * 4]) = o;
        }
        __syncthreads();
#pragma unroll
        for (int ii = 0; ii < 4; ++ii) {
            int i = lane + ii * 64;          // float4 idx within chunk row
            float4 xv = x4[(size_t)m * 1024 + c * 256 + i];
#pragma unroll
            for (int r = 0; r < 16; ++r) {
                ushort4 av = *(const ushort4*)(&As[(r * 256 + i) * 4]);
                acc[r] += xv.x * bf2f(av.x) + xv.y * bf2f(av.y) +
                          xv.z * bf2f(av.z) + xv.w * bf2f(av.w);
            }
        }
    }
#pragma unroll
    for (int r = 0; r < 16; ++r) {
#pragma unroll
        for (int off = 32; off; off >>= 1)
            acc[r] += __shfl_xor(acc[r], off, 64);
    }
    if (lane < 16)
        xb[(size_t)m * KAUG + K_DIM + lane] = f2bf(acc[lane]);
    else if (lane < 32)
        xb[(size_t)m * KAUG + K_DIM + lane] = 0;
}

// ---- main GEMM: out[M][N] = xb[M][KAUG] . wq[N][KAUG]^T (m97 structure) ----
__global__ __launch_bounds__(256) void gemm_kernel(
        const unsigned short* __restrict__ xb,
        const unsigned short* __restrict__ wq,
        float* __restrict__ out) {
    __shared__ __align__(16) unsigned short As[128 * 32];   // 8 KB
    __shared__ __align__(16) unsigned short Bs[128 * 32];   // 8 KB
    const int tid = threadIdx.x;
    const int wave = tid >> 6, lane = tid & 63;
    const int m0 = blockIdx.y * 128;
    const int n0 = blockIdx.x * 128;

    // staging: each wave loads 2x16 rows of A-tile and B-tile via global_load_lds
    const int srow = wave * 32 + (lane >> 2);        // row for j=0 inst
    const int scol = (lane & 3) * 8;                 // k offset (elements)
    const unsigned short* gA0 = xb + (size_t)(m0 + srow) * KAUG + scol;
    const unsigned short* gA1 = gA0 + (size_t)16 * KAUG;
    const unsigned short* gB0 = wq + (size_t)(n0 + srow) * KAUG + scol;
    const unsigned short* gB1 = gB0 + (size_t)16 * KAUG;
    unsigned short* lA0 = As + (wave * 2 + 0) * 512;  // 512 shorts = 1024B/wave-inst
    unsigned short* lA1 = As + (wave * 2 + 1) * 512;
    unsigned short* lB0 = Bs + (wave * 2 + 0) * 512;
    unsigned short* lB1 = Bs + (wave * 2 + 1) * 512;

    // fragment read pointers: wave -> 64x64 subtile (wave&1 = m half, wave>>1 = n half)
    const int fm = lane & 15;
    const int fk = (lane >> 4) * 8;
    const unsigned short* aptr = As + ((wave & 1) * 64 + fm) * 32 + fk;
    const unsigned short* bptr = Bs + ((wave >> 1) * 64 + fm) * 32 + fk;

    f32x4 acc[4][4] = {};

    for (int kt = 0; kt < KTILES; ++kt) {
        __builtin_amdgcn_global_load_lds((const GLOBAL_AS void*)gA0, (LDS_AS void*)lA0, 16, 0, 0);
        __builtin_amdgcn_global_load_lds((const GLOBAL_AS void*)gA1, (LDS_AS void*)lA1, 16, 0, 0);
        __builtin_amdgcn_global_load_lds((const GLOBAL_AS void*)gB0, (LDS_AS void*)lB0, 16, 0, 0);
        __builtin_amdgcn_global_load_lds((const GLOBAL_AS void*)gB1, (LDS_AS void*)lB1, 16, 0, 0);
        gA0 += 32; gA1 += 32; gB0 += 32; gB1 += 32;
        __syncthreads();   // drains vmcnt -> LDS tiles ready

        bf16x8 af[4], bfr[4];
#pragma unroll
        for (int i = 0; i < 4; ++i) {
            af[i]  = *(const bf16x8*)(aptr + i * 16 * 32);
            bfr[i] = *(const bf16x8*)(bptr + i * 16 * 32);
        }
#pragma unroll
        for (int mi = 0; mi < 4; ++mi)
#pragma unroll
            for (int ni = 0; ni < 4; ++ni)
                acc[mi][ni] = __builtin_amdgcn_mfma_f32_16x16x32_bf16(
                    af[mi], bfr[ni], acc[mi][ni], 0, 0, 0);
        __syncthreads();   // all waves done reading before next overwrite
    }

    // epilogue: C/D layout col=lane&15, row=(lane>>4)*4+reg
#pragma unroll
    for (int mi = 0; mi < 4; ++mi) {
#pragma unroll
        for (int ni = 0; ni < 4; ++ni) {
            int col = n0 + (wave >> 1) * 64 + ni * 16 + (lane & 15);
#pragma unroll
            for (int r = 0; r < 4; ++r) {
                int row = m0 + (wave & 1) * 64 + mi * 16 + (lane >> 4) * 4 + r;
                out[(size_t)row * N_DIM + col] = acc[mi][ni][r];
            }
        }
    }
}

extern "C" void kernel_launch(void* const* d_in, const int* in_sizes, int n_in,
                              void* d_out, int out_size, void* d_ws, size_t ws_size,
                              hipStream_t stream) {
    const float* x      = (const float*)d_in[0];
    const int*   codes  = (const int*)d_in[1];
    const float* absmax = (const float*)d_in[2];
    const float* loraA  = (const float*)d_in[3];
    const float* loraB  = (const float*)d_in[4];
    float* out = (float*)d_out;

    unsigned short* xb = (unsigned short*)d_ws;                    // [8192][4128] bf16
    unsigned short* wq = xb + (size_t)M_DIM * KAUG;                // [4096][4128] bf16

    // prep (independent, serialized on stream)
    convert_x_kernel<<<(M_DIM * K_DIM / 4) / 256, 256, 0, stream>>>((const float4*)x, xb);
    dequant_kernel<<<(N_DIM * K_DIM / 4) / 256, 256, 0, stream>>>((const int4*)codes, absmax, wq);
    lora_b_fill_kernel<<<(N_DIM * 32) / 256, 256, 0, stream>>>(loraB, wq);
    lora_a_kernel<<<M_DIM / 4, 256, 0, stream>>>((const float4*)x, (const float4*)loraA, xb);

    // main GEMM
    dim3 grid(N_DIM / 128, M_DIM / 128);
    gemm_kernel<<<grid, 256, 0, stream>>>(xb, wq, out);
}

// Round 2
// 904.827 us; speedup vs baseline: 1.1873x; 1.1873x over previous
//
#include <hip/hip_runtime.h>

#define GLOBAL_AS __attribute__((address_space(1)))
#define LDS_AS    __attribute__((address_space(3)))

typedef short bf16x8 __attribute__((ext_vector_type(8)));
typedef float f32x4  __attribute__((ext_vector_type(4)));

// Problem shape (fixed by setup_inputs)
#define M_DIM 8192     // B*S = 4*2048
#define N_DIM 4096     // DOUT
#define K_DIM 4096     // DIN
#define R_DIM 16
#define KAUG 4160      // K_DIM + 64 (16 lora cols + 48 zero pad) -> 65 tiles of BK=64
#define KTILES 65

__constant__ float NF4C[16] = {
    -1.0f, -0.6961928009986877f, -0.5250730514526367f, -0.39491748809814453f,
    -0.28444138169288635f, -0.18477343022823334f, -0.09105003625154495f, 0.0f,
    0.07958029955625534f, 0.16093020141124725f, 0.24611230194568634f,
    0.33791524171829224f, 0.44070982933044434f, 0.5626170039176941f,
    0.7229568362236023f, 1.0f};

__device__ __forceinline__ unsigned short f2bf(float f) {
    unsigned int u = __float_as_uint(f);
    u += 0x7fffu + ((u >> 16) & 1u);   // round-to-nearest-even
    return (unsigned short)(u >> 16);
}
__device__ __forceinline__ float bf2f(unsigned short s) {
    return __uint_as_float(((unsigned int)s) << 16);
}

// ---- prep A: x fp32 -> bf16 into xb cols 0..4095, PLUS lora_a into cols 4096..4159
// one wave per row m; A staged in LDS as bf16 in 32KB chunks; x read exactly once
__global__ void prep_x_kernel(const float4* __restrict__ x4,
                              const float4* __restrict__ A4,
                              unsigned short* __restrict__ xb) {
    __shared__ __align__(16) unsigned short As[16 * 1024];   // 32 KB chunk of A (bf16)
    const int tid = threadIdx.x;
    const int wave = tid >> 6, lane = tid & 63;
    const int m = blockIdx.x * 4 + wave;
    float acc[16];
#pragma unroll
    for (int r = 0; r < 16; ++r) acc[r] = 0.0f;

    for (int c = 0; c < 4; ++c) {
        __syncthreads();
        // stage A[16][c*1024 .. +1024) as bf16: 4096 float4s, 16/thread
#pragma unroll
        for (int p = 0; p < 16; ++p) {
            int f4 = tid + p * 256;          // 0..4095
            int r = f4 >> 8, kk4 = f4 & 255;
            float4 v = A4[r * 1024 + c * 256 + kk4];
            ushort4 o;
            o.x = f2bf(v.x); o.y = f2bf(v.y); o.z = f2bf(v.z); o.w = f2bf(v.w);
            *(ushort4*)(&As[f4 * 4]) = o;
        }
        __syncthreads();
#pragma unroll
        for (int ii = 0; ii < 4; ++ii) {
            int i = lane + ii * 64;          // float4 idx within chunk row
            int k4 = c * 256 + i;            // float4 idx within full row
            float4 xv = x4[(size_t)m * 1024 + k4];
            // fused convert: write bf16 x
            ushort4 o;
            o.x = f2bf(xv.x); o.y = f2bf(xv.y); o.z = f2bf(xv.z); o.w = f2bf(xv.w);
            *(ushort4*)(xb + (size_t)m * KAUG + k4 * 4) = o;
#pragma unroll
            for (int r = 0; r < 16; ++r) {
                ushort4 av = *(const ushort4*)(&As[(r * 256 + i) * 4]);
                acc[r] += xv.x * bf2f(av.x) + xv.y * bf2f(av.y) +
                          xv.z * bf2f(av.z) + xv.w * bf2f(av.w);
            }
        }
    }
#pragma unroll
    for (int r = 0; r < 16; ++r) {
#pragma unroll
        for (int off = 32; off; off >>= 1)
            acc[r] += __shfl_xor(acc[r], off, 64);
    }
    // cols 4096..4159: 16 lora values then 48 zeros (one short per lane)
    xb[(size_t)m * KAUG + K_DIM + lane] = (lane < 16) ? f2bf(acc[lane]) : (unsigned short)0;
}

// ---- prep B: NF4 dequant -> wq cols 0..4095; threads k4<16 also fill lora cols ----
__global__ void dequant_kernel(const int4* __restrict__ codes4,
                               const float* __restrict__ absmax,
                               const float* __restrict__ loraB,
                               unsigned short* __restrict__ wq) {
    int idx = blockIdx.x * 256 + threadIdx.x;   // int4 index, 4096*1024 total
    int n = idx >> 10;
    int k4 = idx & 1023;
    int k = k4 * 4;
    float am = absmax[n * 64 + (k >> 6)];
    int4 c = codes4[idx];
    ushort4 o;
    o.x = f2bf(NF4C[c.x] * am);
    o.y = f2bf(NF4C[c.y] * am);
    o.z = f2bf(NF4C[c.z] * am);
    o.w = f2bf(NF4C[c.w] * am);
    *(ushort4*)(wq + (size_t)n * KAUG + k) = o;
    if (k4 < 16) {   // fill cols 4096..4159: 2*loraB (16) then zeros (48)
        ushort4 l;
        int c0 = k4 * 4;
        l.x = (c0 + 0 < R_DIM) ? f2bf(2.0f * loraB[n * R_DIM + c0 + 0]) : 0;
        l.y = (c0 + 1 < R_DIM) ? f2bf(2.0f * loraB[n * R_DIM + c0 + 1]) : 0;
        l.z = (c0 + 2 < R_DIM) ? f2bf(2.0f * loraB[n * R_DIM + c0 + 2]) : 0;
        l.w = (c0 + 3 < R_DIM) ? f2bf(2.0f * loraB[n * R_DIM + c0 + 3]) : 0;
        *(ushort4*)(wq + (size_t)n * KAUG + K_DIM + c0) = l;
    }
}

// ---- main GEMM: out[M][N] = xb[M][KAUG] . wq[N][KAUG]^T ----
// BK=64 (32 MFMA per wave per barrier pair), 128B LDS rows with XOR-8 swizzle
__global__ __launch_bounds__(256) void gemm_kernel(
        const unsigned short* __restrict__ xb,
        const unsigned short* __restrict__ wq,
        float* __restrict__ out) {
    __shared__ __align__(16) unsigned short As[128 * 64];   // 16 KB
    __shared__ __align__(16) unsigned short Bs[128 * 64];   // 16 KB
    const int tid = threadIdx.x;
    const int wave = tid >> 6, lane = tid & 63;
    const int m0 = blockIdx.y * 128;
    const int n0 = blockIdx.x * 128;

    // staging: 4 insts/thread per operand; inst j covers rows wave*32+j*8 .. +8
    // lane -> (row = lane>>3, chunkpos = lane&7); fetch global chunk g so that
    // chunkpos = g ^ (row&7)  =>  g = (lane&7) ^ (lane>>3)
    const int srow = lane >> 3;
    const int gcol = ((lane & 7) ^ srow) * 8;     // swizzled k-chunk (elements)
    const unsigned short* gA[4];
    const unsigned short* gB[4];
    unsigned short* lA[4];
    unsigned short* lB[4];
#pragma unroll
    for (int j = 0; j < 4; ++j) {
        int row = wave * 32 + j * 8 + srow;
        gA[j] = xb + (size_t)(m0 + row) * KAUG + gcol;
        gB[j] = wq + (size_t)(n0 + row) * KAUG + gcol;
        lA[j] = As + (wave * 4 + j) * 512;        // 512 shorts = 1 KB per inst
        lB[j] = Bs + (wave * 4 + j) * 512;
    }

    // fragment read: row-local fm, quarter q = lane>>4; swizzled chunk
    const int fm = lane & 15;
    const int q  = lane >> 4;
    // A rows: (wave&1)*64 + mi*16 + fm ; B rows: (wave>>1)*64 + ni*16 + fm
    const unsigned short* aRow = As + ((wave & 1) * 64 + fm) * 64;
    const unsigned short* bRow = Bs + ((wave >> 1) * 64 + fm) * 64;
    const int key = fm & 7;

    f32x4 acc[4][4] = {};

    for (int kt = 0; kt < KTILES; ++kt) {
#pragma unroll
        for (int j = 0; j < 4; ++j) {
            __builtin_amdgcn_global_load_lds((const GLOBAL_AS void*)gA[j], (LDS_AS void*)lA[j], 16, 0, 0);
            __builtin_amdgcn_global_load_lds((const GLOBAL_AS void*)gB[j], (LDS_AS void*)lB[j], 16, 0, 0);
            gA[j] += 64; gB[j] += 64;
        }
        __syncthreads();   // drains vmcnt -> LDS tiles ready

#pragma unroll
        for (int h = 0; h < 2; ++h) {
            const int fk = ((h * 4 + q) ^ key) * 8;   // swizzled element offset
            bf16x8 af[4], bfr[4];
#pragma unroll
            for (int i = 0; i < 4; ++i) {
                af[i]  = *(const bf16x8*)(aRow + i * 16 * 64 + fk);
                bfr[i] = *(const bf16x8*)(bRow + i * 16 * 64 + fk);
            }
#pragma unroll
            for (int mi = 0; mi < 4; ++mi)
#pragma unroll
                for (int ni = 0; ni < 4; ++ni)
                    acc[mi][ni] = __builtin_amdgcn_mfma_f32_16x16x32_bf16(
                        af[mi], bfr[ni], acc[mi][ni], 0, 0, 0);
        }
        __syncthreads();   // all waves done reading before next overwrite
    }

    // epilogue: C/D layout col=lane&15, row=(lane>>4)*4+reg
#pragma unroll
    for (int mi = 0; mi < 4; ++mi) {
#pragma unroll
        for (int ni = 0; ni < 4; ++ni) {
            int col = n0 + (wave >> 1) * 64 + ni * 16 + (lane & 15);
#pragma unroll
            for (int r = 0; r < 4; ++r) {
                int row = m0 + (wave & 1) * 64 + mi * 16 + (lane >> 4) * 4 + r;
                out[(size_t)row * N_DIM + col] = acc[mi][ni][r];
            }
        }
    }
}

extern "C" void kernel_launch(void* const* d_in, const int* in_sizes, int n_in,
                              void* d_out, int out_size, void* d_ws, size_t ws_size,
                              hipStream_t stream) {
    const float* x      = (const float*)d_in[0];
    const int*   codes  = (const int*)d_in[1];
    const float* absmax = (const float*)d_in[2];
    const float* loraA  = (const float*)d_in[3];
    const float* loraB  = (const float*)d_in[4];
    float* out = (float*)d_out;

    unsigned short* xb = (unsigned short*)d_ws;                    // [8192][4160] bf16
    unsigned short* wq = xb + (size_t)M_DIM * KAUG;                // [4096][4160] bf16

    prep_x_kernel<<<M_DIM / 4, 256, 0, stream>>>((const float4*)x, (const float4*)loraA, xb);
    dequant_kernel<<<(N_DIM * K_DIM / 4) / 256, 256, 0, stream>>>(
        (const int4*)codes, absmax, loraB, wq);

    dim3 grid(N_DIM / 128, M_DIM / 128);
    gemm_kernel<<<grid, 256, 0, stream>>>(xb, wq, out);
}